// Round 5
// baseline (276.905 us; speedup 1.0000x reference)
//
#include <hip/hip_runtime.h>

#define TSC_OUT_LEN 16384
#define TSC_ENC_LEN 16368   // 16384 - 16384/1024

// readfirstlane on a float: forces a block/wave-uniform value into an SGPR.
__device__ __forceinline__ float tsc_rfl(float x) {
    return __uint_as_float(__builtin_amdgcn_readfirstlane(__float_as_uint(x)));
}

// out[b,j] = sum_{e=1..10} data[b, off_e + (j>>e)] * weights[(2^e-1) + (j&(2^e-1))] + sum_e bias[e-1]
//
// R4 post-mortem: request-size theory falsified (2.5x fewer VMEM instrs, same
// 84 us). R0/R2/R4 all pin at ~2.45 TB/s with waves ~98% stalled -> loaded
// latency ~10x unloaded = queueing at a saturated point. Remaining diff vs the
// 6.3 TB/s copy kernel: OUR streams are 8B..2KB pieces at ~64KB strides (DRAM
// page-miss per visit); copy's are long sequential runs.
//
// Fix: one-shot half-row blocks. grid 4096 = (row, half). Each block:
//   1. stages its half-row's coefficients (8184 floats) as 10 CONTIGUOUS
//      region bursts, packed into 32 KB of LDS (float4-only, 8 slots/thread),
//   2. computes all 8192 outputs of the half from LDS (weights in regs,
//      invariant across the 4 j-tiles since 2048 = 0 mod 2^e for e<=10),
//   3. writes one sequential 32 KB output burst.
// HBM-visible pattern == copy kernel. LDS 8KB(wl)+32KB(dL) -> 4 blocks/CU.
//
// dL packed layout (floats): e1 [0,4096) e2 [4096,6144) e3 [6144,7168)
// e4 [7168,7680) e5 [7680,7936) e6 [7936,8064) e7 [8064,8128) e8 [8128,8160)
// e9 [8160,8176) e10 [8176,8184). Slot s (float4 units) maps linearly.
__global__ __launch_bounds__(256, 2) void tsc_transpose_kernel(
    const float* __restrict__ data,
    const float* __restrict__ weights,
    const float* __restrict__ bias,
    float* __restrict__ out)
{
    __shared__ float wl[2048];
    __shared__ __align__(16) float dL[8184];

    const int tid  = threadIdx.x;
    const int b    = blockIdx.x >> 1;
    const int half = blockIdx.x & 1;
    const float* drow = data + (size_t)b * TSC_ENC_LEN;

    // ---- map the 2046 float4 slots to global region addresses (init-only) --
    const float4* gaddr[8];
#pragma unroll
    for (int k = 0; k < 8; ++k) {
        const int s = tid + (k << 8);
        int e, base;
        if      (s < 1024) { e = 1;  base = 0;    }
        else if (s < 1536) { e = 2;  base = 1024; }
        else if (s < 1792) { e = 3;  base = 1536; }
        else if (s < 1920) { e = 4;  base = 1792; }
        else if (s < 1984) { e = 5;  base = 1920; }
        else if (s < 2016) { e = 6;  base = 1984; }
        else if (s < 2032) { e = 7;  base = 2016; }
        else if (s < 2040) { e = 8;  base = 2032; }
        else if (s < 2044) { e = 9;  base = 2040; }
        else               { e = 10; base = 2044; }
        const int off_e  = TSC_OUT_LEN - (32768 >> e);   // region start in row
        const int half_e = 8192 >> e;                    // floats per half
        gaddr[k] = reinterpret_cast<const float4*>(drow + off_e + half * half_e)
                   + (s - base);
    }
    // Issue all 8 staging loads first (independent, all in flight together).
    float4 sv[8];
#pragma unroll
    for (int k = 0; k < 8; ++k) {
        const int s = tid + (k << 8);
        if (s < 2046) sv[k] = *gaddr[k];
    }
    // Weights -> LDS, +1 shift so runs starting at 2^e-1 are 16B aligned.
    for (int i = tid; i < 2047; i += 256) wl[i + 1] = weights[i];
    // Land the staged data in LDS (packed, slot-linear).
#pragma unroll
    for (int k = 0; k < 8; ++k) {
        const int s = tid + (k << 8);
        if (s < 2046) reinterpret_cast<float4*>(dL)[s] = sv[k];
    }
    __syncthreads();

    // Sum of all per-scale biases — one constant added to every output.
    float bs = 0.0f;
#pragma unroll
    for (int i = 0; i < 10; ++i) bs += bias[i];

    // e=1..3 weights: identical for every thread -> SGPRs.
    const float w1a = tsc_rfl(wl[2]), w1b = tsc_rfl(wl[3]);
    const float w2a = tsc_rfl(wl[4]), w2b = tsc_rfl(wl[5]);
    const float w2c = tsc_rfl(wl[6]), w2d = tsc_rfl(wl[7]);
    float w3[8];
#pragma unroll
    for (int i = 0; i < 8; ++i) w3[i] = tsc_rfl(wl[8 + i]);

    // e=4..10 weights: fixed per thread (invariant across the 4 j-tiles).
    const int j8 = tid << 3;
    float4 wa[7], wb[7];
#pragma unroll
    for (int e = 4; e <= 10; ++e) {
        const int w  = 1 << e;
        const int kb = w + (j8 & (w - 1));   // 8-aligned -> 16B-aligned reads
        wa[e - 4] = *reinterpret_cast<const float4*>(&wl[kb]);
        wb[e - 4] = *reinterpret_cast<const float4*>(&wl[kb + 4]);
    }

    float* orow = out + (size_t)b * TSC_OUT_LEN + (half << 13) + j8;

#pragma unroll 2
    for (int it = 0; it < 4; ++it) {
        const int jl = (it << 11) + j8;      // local output index in the half
        const float4 c1 = *reinterpret_cast<const float4*>(&dL[jl >> 1]);
        const float2 c2 = *reinterpret_cast<const float2*>(&dL[4096 + (jl >> 2)]);
        const float c3  = dL[6144 + (jl >> 3)];
        const float c4  = dL[7168 + (jl >> 4)];
        const float c5  = dL[7680 + (jl >> 5)];
        const float c6  = dL[7936 + (jl >> 6)];
        const float c7  = dL[8064 + (jl >> 7)];
        const float c8  = dL[8128 + (jl >> 8)];
        const float c9  = dL[8160 + (jl >> 9)];
        const float c10 = dL[8176 + (jl >> 10)];

        float a0 = bs, a1 = bs, a2 = bs, a3 = bs;
        float a4 = bs, a5 = bs, a6 = bs, a7 = bs;
        // e = 1
        a0 = fmaf(c1.x, w1a, a0); a1 = fmaf(c1.x, w1b, a1);
        a2 = fmaf(c1.y, w1a, a2); a3 = fmaf(c1.y, w1b, a3);
        a4 = fmaf(c1.z, w1a, a4); a5 = fmaf(c1.z, w1b, a5);
        a6 = fmaf(c1.w, w1a, a6); a7 = fmaf(c1.w, w1b, a7);
        // e = 2
        a0 = fmaf(c2.x, w2a, a0); a1 = fmaf(c2.x, w2b, a1);
        a2 = fmaf(c2.x, w2c, a2); a3 = fmaf(c2.x, w2d, a3);
        a4 = fmaf(c2.y, w2a, a4); a5 = fmaf(c2.y, w2b, a5);
        a6 = fmaf(c2.y, w2c, a6); a7 = fmaf(c2.y, w2d, a7);
        // e = 3
        a0 = fmaf(c3, w3[0], a0); a1 = fmaf(c3, w3[1], a1);
        a2 = fmaf(c3, w3[2], a2); a3 = fmaf(c3, w3[3], a3);
        a4 = fmaf(c3, w3[4], a4); a5 = fmaf(c3, w3[5], a5);
        a6 = fmaf(c3, w3[6], a6); a7 = fmaf(c3, w3[7], a7);
        // e = 4..10
#define TSC_E(c, i) \
        a0 = fmaf(c, wa[i].x, a0); a1 = fmaf(c, wa[i].y, a1); \
        a2 = fmaf(c, wa[i].z, a2); a3 = fmaf(c, wa[i].w, a3); \
        a4 = fmaf(c, wb[i].x, a4); a5 = fmaf(c, wb[i].y, a5); \
        a6 = fmaf(c, wb[i].z, a6); a7 = fmaf(c, wb[i].w, a7);
        TSC_E(c4, 0)
        TSC_E(c5, 1)
        TSC_E(c6, 2)
        TSC_E(c7, 3)
        TSC_E(c8, 4)
        TSC_E(c9, 5)
        TSC_E(c10, 6)
#undef TSC_E
        float4* o4 = reinterpret_cast<float4*>(orow + (it << 11));
        o4[0] = make_float4(a0, a1, a2, a3);
        o4[1] = make_float4(a4, a5, a6, a7);
    }
}

extern "C" void kernel_launch(void* const* d_in, const int* in_sizes, int n_in,
                              void* d_out, int out_size, void* d_ws, size_t ws_size,
                              hipStream_t stream) {
    const float* data    = (const float*)d_in[0];
    const float* weights = (const float*)d_in[1];
    const float* bias    = (const float*)d_in[2];
    float* out = (float*)d_out;

    const int B = in_sizes[0] / TSC_ENC_LEN;   // 2048
    dim3 grid(B * 2);                          // (row, half) one-shot blocks
    dim3 block(256);
    tsc_transpose_kernel<<<grid, block, 0, stream>>>(data, weights, bias, out);
}

// Round 6
// 241.411 us; speedup vs baseline: 1.1470x; 1.1470x over previous
//
#include <hip/hip_runtime.h>

#define TSC_OUT_LEN 16384
#define TSC_ENC_LEN 16368   // 16384 - 16384/1024

// readfirstlane on a float: forces a block/wave-uniform value into an SGPR.
__device__ __forceinline__ float tsc_rfl(float x) {
    return __uint_as_float(__builtin_amdgcn_readfirstlane(__float_as_uint(x)));
}

// out[b,j] = sum_{e=1..10} data[b, off_e + (j>>e)] * weights[(2^e-1) + (j&(2^e-1))] + sum_e bias[e-1]
//
// R5 post-mortem: sequential-burst staging raised BW 2.45->3.45 TB/s (theory
// confirmed) but the global->VGPR->LDS round-trip spilled (~190 MB scratch
// traffic, FETCH 132 / WRITE 263 MB) and ate the win.
//
// R6: same one-shot half-row blocks (grid 4096 = (row, half)), but:
//  - staging via __builtin_amdgcn_global_load_lds width=16: global->LDS DMA,
//    ZERO data VGPRs, no spill. Per-lane global source (region-decoded slot),
//    wave-uniform LDS dest base (slot-linear packed layout).
//  - only e=2..10 staged (4088 floats/half -> 16 KB dL). The e=1 region is
//    read directly during compute as float4s: consecutive lanes -> 1 KB/instr
//    sequential bursts already, staging it was pure overhead.
//  - LDS 8 KB (wl) + 16 KB (dL) = 24 KB -> 6 blocks/CU; one-shot blocks
//    phase-stagger across the CU (some stage while others compute).
// dL packed layout (floats): e2 [0,2048) e3 [2048,3072) e4 [3072,3584)
// e5 [3584,3840) e6 [3840,3968) e7 [3968,4032) e8 [4032,4064)
// e9 [4064,4080) e10 [4080,4088); slots 1022/1023 are clamped garbage.
__global__ __launch_bounds__(256, 4) void tsc_transpose_kernel(
    const float* __restrict__ data,
    const float* __restrict__ weights,
    const float* __restrict__ bias,
    float* __restrict__ out)
{
    __shared__ float wl[2048];
    __shared__ __align__(16) float dL[4096];

    const int tid  = threadIdx.x;
    const int b    = blockIdx.x >> 1;
    const int half = blockIdx.x & 1;
    const float* drow = data + (size_t)b * TSC_ENC_LEN;

    // ---- stage e=2..10 coefficient regions: global -> LDS direct ----------
    // 1024 float4 slots; wave w handles slot chunks cid = 4w..4w+3 (64/call).
    const int lane = tid & 63;
    const int w_u  = __builtin_amdgcn_readfirstlane(tid >> 6);
#pragma unroll
    for (int k = 0; k < 4; ++k) {
        const int cid = k + (w_u << 2);      // wave-uniform chunk id, 0..15
        const int s   = lane + (cid << 6);   // slot 0..1023 (per-lane)
        int e, base;
        if      (s < 512)  { e = 2;  base = 0;    }
        else if (s < 768)  { e = 3;  base = 512;  }
        else if (s < 896)  { e = 4;  base = 768;  }
        else if (s < 960)  { e = 5;  base = 896;  }
        else if (s < 992)  { e = 6;  base = 960;  }
        else if (s < 1008) { e = 7;  base = 992;  }
        else if (s < 1016) { e = 8;  base = 1008; }
        else if (s < 1020) { e = 9;  base = 1016; }
        else               { e = 10; base = 1020; }
        // region start + half offset + slot offset (all 16B aligned)
        const int off = TSC_OUT_LEN - (32768 >> e) + (half << (13 - e))
                        + ((s - base) << 2);
        const float* gs = (s < 1022) ? (drow + off) : drow;  // clamp 2 pad slots
        __builtin_amdgcn_global_load_lds(
            (const __attribute__((address_space(1))) unsigned int*)gs,
            (__attribute__((address_space(3))) unsigned int*)(dL + (cid << 8)),
            16, 0, 0);
    }

    // e=1 prefetch (direct, already sequential): 4 float4 per thread.
    const float* p1 = drow + (half << 12) + (tid << 2);
    const float4 c1a = *reinterpret_cast<const float4*>(p1);
    const float4 c1b = *reinterpret_cast<const float4*>(p1 + 1024);
    const float4 c1c = *reinterpret_cast<const float4*>(p1 + 2048);
    const float4 c1d = *reinterpret_cast<const float4*>(p1 + 3072);

    // Weights -> LDS, +1 shift so runs starting at 2^e-1 are 16B aligned.
    for (int i = tid; i < 2047; i += 256) wl[i + 1] = weights[i];

    // Sum of all per-scale biases — one constant added to every output.
    float bs = 0.0f;
#pragma unroll
    for (int i = 0; i < 10; ++i) bs += bias[i];

    __syncthreads();   // drains vmcnt (global_load_lds) + lgkmcnt (wl writes)

    // e=1..3 weights: identical for every thread -> SGPRs.
    const float w1a = tsc_rfl(wl[2]), w1b = tsc_rfl(wl[3]);
    const float w2a = tsc_rfl(wl[4]), w2b = tsc_rfl(wl[5]);
    const float w2c = tsc_rfl(wl[6]), w2d = tsc_rfl(wl[7]);
    float w3[8];
#pragma unroll
    for (int i = 0; i < 8; ++i) w3[i] = tsc_rfl(wl[8 + i]);

    // e=4..10 weights: fixed per thread (invariant across the 4 j-tiles,
    // since 2048 == 0 mod 2^e for e<=10).
    const int j8 = tid << 3;
    float4 wa[7], wb[7];
#pragma unroll
    for (int e = 4; e <= 10; ++e) {
        const int w  = 1 << e;
        const int kb = w + (j8 & (w - 1));   // 8-aligned -> 16B-aligned reads
        wa[e - 4] = *reinterpret_cast<const float4*>(&wl[kb]);
        wb[e - 4] = *reinterpret_cast<const float4*>(&wl[kb + 4]);
    }

    float* orow = out + (size_t)b * TSC_OUT_LEN + (half << 13) + j8;

#define TSC_ITER(IT, C1) do {                                              \
        const int jl = ((IT) << 11) + j8;                                  \
        const float2 c2 = *reinterpret_cast<const float2*>(&dL[jl >> 2]);  \
        const float c3  = dL[2048 + (jl >> 3)];                            \
        const float c4  = dL[3072 + (jl >> 4)];                            \
        const float c5  = dL[3584 + (jl >> 5)];                            \
        const float c6  = dL[3840 + (jl >> 6)];                            \
        const float c7  = dL[3968 + (jl >> 7)];                            \
        const float c8  = dL[4032 + (jl >> 8)];                            \
        const float c9  = dL[4064 + (jl >> 9)];                            \
        const float c10 = dL[4080 + (jl >> 10)];                           \
        float a0 = bs, a1 = bs, a2 = bs, a3 = bs;                          \
        float a4 = bs, a5 = bs, a6 = bs, a7 = bs;                          \
        a0 = fmaf((C1).x, w1a, a0); a1 = fmaf((C1).x, w1b, a1);            \
        a2 = fmaf((C1).y, w1a, a2); a3 = fmaf((C1).y, w1b, a3);            \
        a4 = fmaf((C1).z, w1a, a4); a5 = fmaf((C1).z, w1b, a5);            \
        a6 = fmaf((C1).w, w1a, a6); a7 = fmaf((C1).w, w1b, a7);            \
        a0 = fmaf(c2.x, w2a, a0); a1 = fmaf(c2.x, w2b, a1);                \
        a2 = fmaf(c2.x, w2c, a2); a3 = fmaf(c2.x, w2d, a3);                \
        a4 = fmaf(c2.y, w2a, a4); a5 = fmaf(c2.y, w2b, a5);                \
        a6 = fmaf(c2.y, w2c, a6); a7 = fmaf(c2.y, w2d, a7);                \
        a0 = fmaf(c3, w3[0], a0); a1 = fmaf(c3, w3[1], a1);                \
        a2 = fmaf(c3, w3[2], a2); a3 = fmaf(c3, w3[3], a3);                \
        a4 = fmaf(c3, w3[4], a4); a5 = fmaf(c3, w3[5], a5);                \
        a6 = fmaf(c3, w3[6], a6); a7 = fmaf(c3, w3[7], a7);                \
        a0 = fmaf(c4, wa[0].x, a0); a1 = fmaf(c4, wa[0].y, a1);            \
        a2 = fmaf(c4, wa[0].z, a2); a3 = fmaf(c4, wa[0].w, a3);            \
        a4 = fmaf(c4, wb[0].x, a4); a5 = fmaf(c4, wb[0].y, a5);            \
        a6 = fmaf(c4, wb[0].z, a6); a7 = fmaf(c4, wb[0].w, a7);            \
        a0 = fmaf(c5, wa[1].x, a0); a1 = fmaf(c5, wa[1].y, a1);            \
        a2 = fmaf(c5, wa[1].z, a2); a3 = fmaf(c5, wa[1].w, a3);            \
        a4 = fmaf(c5, wb[1].x, a4); a5 = fmaf(c5, wb[1].y, a5);            \
        a6 = fmaf(c5, wb[1].z, a6); a7 = fmaf(c5, wb[1].w, a7);            \
        a0 = fmaf(c6, wa[2].x, a0); a1 = fmaf(c6, wa[2].y, a1);            \
        a2 = fmaf(c6, wa[2].z, a2); a3 = fmaf(c6, wa[2].w, a3);            \
        a4 = fmaf(c6, wb[2].x, a4); a5 = fmaf(c6, wb[2].y, a5);            \
        a6 = fmaf(c6, wb[2].z, a6); a7 = fmaf(c6, wb[2].w, a7);            \
        a0 = fmaf(c7, wa[3].x, a0); a1 = fmaf(c7, wa[3].y, a1);            \
        a2 = fmaf(c7, wa[3].z, a2); a3 = fmaf(c7, wa[3].w, a3);            \
        a4 = fmaf(c7, wb[3].x, a4); a5 = fmaf(c7, wb[3].y, a5);            \
        a6 = fmaf(c7, wb[3].z, a6); a7 = fmaf(c7, wb[3].w, a7);            \
        a0 = fmaf(c8, wa[4].x, a0); a1 = fmaf(c8, wa[4].y, a1);            \
        a2 = fmaf(c8, wa[4].z, a2); a3 = fmaf(c8, wa[4].w, a3);            \
        a4 = fmaf(c8, wb[4].x, a4); a5 = fmaf(c8, wb[4].y, a5);            \
        a6 = fmaf(c8, wb[4].z, a6); a7 = fmaf(c8, wb[4].w, a7);            \
        a0 = fmaf(c9, wa[5].x, a0); a1 = fmaf(c9, wa[5].y, a1);            \
        a2 = fmaf(c9, wa[5].z, a2); a3 = fmaf(c9, wa[5].w, a3);            \
        a4 = fmaf(c9, wb[5].x, a4); a5 = fmaf(c9, wb[5].y, a5);            \
        a6 = fmaf(c9, wb[5].z, a6); a7 = fmaf(c9, wb[5].w, a7);            \
        a0 = fmaf(c10, wa[6].x, a0); a1 = fmaf(c10, wa[6].y, a1);          \
        a2 = fmaf(c10, wa[6].z, a2); a3 = fmaf(c10, wa[6].w, a3);          \
        a4 = fmaf(c10, wb[6].x, a4); a5 = fmaf(c10, wb[6].y, a5);          \
        a6 = fmaf(c10, wb[6].z, a6); a7 = fmaf(c10, wb[6].w, a7);          \
        float4* o4 = reinterpret_cast<float4*>(orow + ((IT) << 11));       \
        o4[0] = make_float4(a0, a1, a2, a3);                               \
        o4[1] = make_float4(a4, a5, a6, a7);                               \
    } while (0)

    TSC_ITER(0, c1a);
    TSC_ITER(1, c1b);
    TSC_ITER(2, c1c);
    TSC_ITER(3, c1d);
#undef TSC_ITER
}

extern "C" void kernel_launch(void* const* d_in, const int* in_sizes, int n_in,
                              void* d_out, int out_size, void* d_ws, size_t ws_size,
                              hipStream_t stream) {
    const float* data    = (const float*)d_in[0];
    const float* weights = (const float*)d_in[1];
    const float* bias    = (const float*)d_in[2];
    float* out = (float*)d_out;

    const int B = in_sizes[0] / TSC_ENC_LEN;   // 2048
    dim3 grid(B * 2);                          // (row, half) one-shot blocks
    dim3 block(256);
    tsc_transpose_kernel<<<grid, block, 0, stream>>>(data, weights, bias, out);
}